// Round 20
// baseline (267.942 us; speedup 1.0000x reference)
//
#include <hip/hip_runtime.h>

#define NROWS 65536
#define KC    1024
#define DD    256
#define ND    (NROWS*DD)      /* 16777216 */
#define KD    (KC*DD)         /* 262144 */
#define BROWS 64              /* rows per screen block */
#define CAP   32              /* LDS candidate list capacity per row */
#define CEXP  12              /* exported (filtered) candidates per row */
#define MARGIN 3.0f           /* >=2E for bf16-screen vs exact-replica (~14 sigma) */

/* output offsets (floats), concatenated in reference return order */
#define O_ZQ   0
#define O_DIST ND
#define O_IDX  (ND+1)
#define O_EMB  (ND+1+NROWS)
#define O_MT   (O_EMB+KD)
#define O_NT   (O_MT+KD)

/* ws float offsets */
#define WS_WSQ   0
#define WS_WPK   KC                    /* 131072 floats = 512KB bf16 W frags */
#define WS_ROWC  (KC+131072)           /* NROWS ints */
#define WS_BUCK  (WS_ROWC+NROWS)       /* NROWS ints */
#define WS_OFFS  (WS_BUCK+NROWS)       /* 1028 ints (1025 used) */
#define WS_POS   (WS_OFFS+1028)        /* KC ints */
#define WS_CNT   (WS_POS+KC)           /* KC ints */
#define WS_DIST  (WS_CNT+KC)           /* 1 float + 3 pad (legacy slot) */
#define WS_ST    (WS_DIST+4)           /* KD floats */
#define WS_CAND  (WS_ST+KD)            /* NROWS*CEXP u16 */
#define WS_SEL   (WS_CAND+NROWS*CEXP/2)/* NROWS u16 -> NROWS/2 floats */
#define WS_DISTP (WS_SEL+NROWS/2)      /* 2048 floats: per-block dist partials */

typedef __attribute__((ext_vector_type(8))) short bf16x8;
typedef __attribute__((ext_vector_type(4))) float f32x4;

/* ===== exact-replica arithmetic contract (validated rounds 5-19) =====
   ref dist d2[r][c] = fadd( fsub( zsq[r], fmul(2, dot) ), wsq[c] )
   dot  = sequential ascending-k, SEPARATE mul+add roundings, single acc
   zsq/wsq = strict sequential sum of squares (mul+add, ascending)
   argmin  = first occurrence of min.
   Screen = bf16 MFMA (row-constant zsq dropped, absorbed in MARGIN);
   every code within MARGIN of the row's global screen min is rescored
   with the exact chain.
   This round vs r19 (screen/decide/prefix/scatter byte-identical):
   - zq re-split from chunksum: row-ordered sequential ze read + out write
     (r15's zq flaw — 8192 wave-atomics on ONE dist address — replaced by
     per-block partials), rowcode loads hoisted for MLP.
   - chunksum: pure st segmented-sum (no out/W/dist work). */

static __device__ __forceinline__ void minmerge(float& bv, int& bi, float ov, int oi){
  if (ov < bv || (ov == bv && oi < bi)) { bv = ov; bi = oi; }
}

static __device__ __forceinline__ unsigned short f2bf(float f){
  unsigned u = __float_as_uint(f);
  unsigned r = (u + 0x7FFFu + ((u>>16)&1u)) >> 16;   /* RNE */
  return (unsigned short)r;
}
static __device__ __forceinline__ bf16x8 cvt8(float4 a, float4 b){
  bf16x8 v;
  v[0]=(short)f2bf(a.x); v[1]=(short)f2bf(a.y); v[2]=(short)f2bf(a.z); v[3]=(short)f2bf(a.w);
  v[4]=(short)f2bf(b.x); v[5]=(short)f2bf(b.y); v[6]=(short)f2bf(b.z); v[7]=(short)f2bf(b.w);
  return v;
}

/* prologue: one wave per code. Lanes 0-31 pack bf16 B-fragments,
   lane 32 runs the exact wsq chain (scalar, round-11 verbatim). */
__global__ __launch_bounds__(256,1) void vq_prep_kernel(const float* __restrict__ W,
                                                        float* __restrict__ wsq,
                                                        bf16x8* __restrict__ wpk){
  const int wv = threadIdx.x>>6, lane = threadIdx.x&63;
  const int k = blockIdx.x*4 + wv;
  const float* wr = W + (size_t)k*DD;
  if (lane < 32){
    float4 x = *(const float4*)(wr + lane*8);
    float4 y = *(const float4*)(wr + lane*8 + 4);
    wpk[((k>>4)*8 + (lane>>2))*64 + (k&15) + 16*(lane&3)] = cvt8(x,y);
  } else if (lane == 32){
    float s = __fmul_rn(wr[0], wr[0]);
    for (int i=1;i<256;i++) s = __fadd_rn(s, __fmul_rn(wr[i], wr[i]));
    wsq[k] = s;
  }
}

/* screenA: r18 verbatim. 512 thr = 8 waves, 64 rows x 1024 codes per block,
   4 col passes of 64 -> acc[2][4], no spill at the arg2=4 cap (64). */
__global__ __launch_bounds__(512,4) void vq_screen_kernel(
    const float* __restrict__ ze, const bf16x8* __restrict__ wpk,
    const float* __restrict__ wsq,
    unsigned short* __restrict__ cand, unsigned short* __restrict__ selw)
{
  __shared__ bf16x8 apkS[2048];        /* 32 KB: A fragments, linear */
  __shared__ float  wsqS[KC];          /* 4 KB */
  __shared__ float  gminW[16][BROWS];  /* 4 KB: per-(pass,cg) row mins */
  __shared__ int    cntS[BROWS];
  __shared__ float  listV[BROWS][CAP]; /* 8 KB */
  __shared__ int    listI[BROWS][CAP]; /* 8 KB */

  const int tid = threadIdx.x;
  const int blk = blockIdx.x;
  const float* zb = ze + (size_t)blk*BROWS*DD;

  /* ---- phase 1: convert z tile to A fragments + init ---- */
  #pragma unroll
  for (int it=0; it<4; ++it){
    const int g  = it*512 + tid;
    const int r  = g >> 5;
    const int kb = g & 31;
    float4 a = *(const float4*)&zb[(size_t)r*DD + kb*8];
    float4 b = *(const float4*)&zb[(size_t)r*DD + kb*8 + 4];
    apkS[((r>>4)*8 + (kb>>2))*64 + (r&15) + 16*(kb&3)] = cvt8(a,b);
  }
  wsqS[tid]     = wsq[tid];
  wsqS[tid+512] = wsq[tid+512];
  if (tid < BROWS) cntS[tid] = 0;
  __syncthreads();

  /* ---- phase 2: MFMA screen + per-group min + candidate collection ---- */
  const int lane = tid & 63;
  const int wv   = tid >> 6;
  const int rg   = wv >> 2;
  const int cg   = wv & 3;

  for (int p=0; p<4; ++p){
    f32x4 acc[2][4];
    #pragma unroll
    for (int mt=0; mt<2; ++mt)
      #pragma unroll
      for (int nt=0; nt<4; ++nt)
        acc[mt][nt] = (f32x4){0.f,0.f,0.f,0.f};

    #pragma unroll
    for (int s=0; s<8; ++s){
      bf16x8 af[2], bf[4];
      #pragma unroll
      for (int mt=0; mt<2; ++mt)
        af[mt] = apkS[((rg*2+mt)*8 + s)*64 + lane];
      #pragma unroll
      for (int nt=0; nt<4; ++nt)
        bf[nt] = wpk[(size_t)(((cg*16 + p*4 + nt)*8 + s)*64 + lane)];
      #pragma unroll
      for (int mt=0; mt<2; ++mt)
        #pragma unroll
        for (int nt=0; nt<4; ++nt)
          acc[mt][nt] = __builtin_amdgcn_mfma_f32_16x16x32_bf16(af[mt], bf[nt], acc[mt][nt], 0,0,0);
    }

    /* screen value = wsq - 2*dot (row-constant zsq dropped) */
    #pragma unroll
    for (int mt=0; mt<2; ++mt){
      #pragma unroll
      for (int r=0; r<4; ++r){
        const int row = rg*32 + mt*16 + (lane>>4)*4 + r;
        float dv[4]; float mn = 3.4e38f;
        #pragma unroll
        for (int nt=0; nt<4; ++nt){
          const int col = (cg*16 + p*4 + nt)*16 + (lane&15);
          dv[nt] = __fsub_rn(wsqS[col], __fmul_rn(2.0f, acc[mt][nt][r]));
          mn = fminf(mn, dv[nt]);
        }
        #pragma unroll
        for (int m=1; m<16; m<<=1) mn = fminf(mn, __shfl_xor(mn, m));
        if ((lane & 15) == 0) gminW[p*4+cg][row] = mn;
        const float thr = mn + MARGIN;
        #pragma unroll
        for (int nt=0; nt<4; ++nt){
          if (dv[nt] <= thr){
            int slot = atomicAdd(&cntS[row], 1);
            if (slot < CAP){
              listV[row][slot] = dv[nt];
              listI[row][slot] = (cg*16 + p*4 + nt)*16 + (lane&15);
            }
          }
        }
      }
    }
  }
  __syncthreads();

  /* ---- phase 3': global-min filter + export ---- */
  if (tid < BROWS){
    const int rr = tid;
    float g = gminW[0][rr];
    #pragma unroll
    for (int q=1;q<16;q++) g = fminf(g, gminW[q][rr]);
    const float fthr = g + MARGIN;
    int c = cntS[rr]; if (c > CAP) c = CAP;
    const int grow = blk*BROWS + rr;
    int sel = 0;
    for (int i=0;i<c;i++){
      if (listV[rr][i] <= fthr && sel < CEXP){
        cand[(size_t)grow*CEXP + sel] = (unsigned short)listI[rr][i];
        sel++;
      }
    }
    selw[grow] = (unsigned short)sel;
  }
}

/* decideB: r19 verbatim. 1 thread/row, chains value-identical to r11. */
__global__ __launch_bounds__(256,1) void vq_decide_kernel(
    const float* __restrict__ ze, const float* __restrict__ W,
    const float* __restrict__ wsq,
    const unsigned short* __restrict__ cand, const unsigned short* __restrict__ selw,
    int* __restrict__ rowcode, int* __restrict__ cnt, float* __restrict__ out)
{
  const int row = blockIdx.x*256 + threadIdx.x;
  const float4* z4p = (const float4*)(ze + (size_t)row*DD);
  const int sel = selw[row];
  float bv = 3.4e38f; int bi = 0x7fffffff;

  if (sel > 0){
    const int idx0 = cand[(size_t)row*CEXP];
    const float4* w4p = (const float4*)(W + (size_t)idx0*DD);
    float4 z = z4p[0], w = w4p[0];
    float zs = __fmul_rn(z.x, z.x);
    float ss = __fadd_rn(0.f, __fmul_rn(z.x, w.x));
    zs = __fadd_rn(zs, __fmul_rn(z.y, z.y)); ss = __fadd_rn(ss, __fmul_rn(z.y, w.y));
    zs = __fadd_rn(zs, __fmul_rn(z.z, z.z)); ss = __fadd_rn(ss, __fmul_rn(z.z, w.z));
    zs = __fadd_rn(zs, __fmul_rn(z.w, z.w)); ss = __fadd_rn(ss, __fmul_rn(z.w, w.w));
    for (int k4=1; k4<64; ++k4){
      z = z4p[k4]; w = w4p[k4];
      zs = __fadd_rn(zs, __fmul_rn(z.x, z.x)); ss = __fadd_rn(ss, __fmul_rn(z.x, w.x));
      zs = __fadd_rn(zs, __fmul_rn(z.y, z.y)); ss = __fadd_rn(ss, __fmul_rn(z.y, w.y));
      zs = __fadd_rn(zs, __fmul_rn(z.z, z.z)); ss = __fadd_rn(ss, __fmul_rn(z.z, w.z));
      zs = __fadd_rn(zs, __fmul_rn(z.w, z.w)); ss = __fadd_rn(ss, __fmul_rn(z.w, w.w));
    }
    {
      const float v = __fadd_rn(__fsub_rn(zs, __fmul_rn(2.0f, ss)), wsq[idx0]);
      minmerge(bv, bi, v, idx0);
    }
    for (int i=1; i<sel; ++i){
      const int idx = cand[(size_t)row*CEXP + i];
      const float4* wp = (const float4*)(W + (size_t)idx*DD);
      float s2 = 0.f;
      for (int k4=0; k4<64; ++k4){
        float4 zz = z4p[k4], ww = wp[k4];
        s2 = __fadd_rn(s2, __fmul_rn(zz.x, ww.x));
        s2 = __fadd_rn(s2, __fmul_rn(zz.y, ww.y));
        s2 = __fadd_rn(s2, __fmul_rn(zz.z, ww.z));
        s2 = __fadd_rn(s2, __fmul_rn(zz.w, ww.w));
      }
      const float v = __fadd_rn(__fsub_rn(zs, __fmul_rn(2.0f, s2)), wsq[idx]);
      minmerge(bv, bi, v, idx);
    }
  }
  rowcode[row] = bi;
  out[O_IDX + row] = (float)bi;
  atomicAdd(&cnt[bi], 1);
}

/* zqC: row-ordered, fully-coalesced zq_st + dist. 64 consecutive lanes share
   one row; ze read + out write sequential. rowcode loads hoisted (MLP);
   dist via per-block partials (no global atomics). grid 2048. */
__global__ __launch_bounds__(256,4) void vq_zq_kernel(
    const float* __restrict__ ze, const float* __restrict__ W,
    const int* __restrict__ rowcode, float* __restrict__ out,
    float* __restrict__ dist_part)
{
  __shared__ float dps[4];
  const int t = blockIdx.x*256 + threadIdx.x;    /* 0..524287 */
  int gi[8];
  #pragma unroll
  for (int it=0; it<8; ++it)
    gi[it] = rowcode[(it*524288 + t) >> 6];
  float distp = 0.f;
  #pragma unroll
  for (int it=0; it<8; ++it){
    const int fi = it*524288 + t;                /* float4 index < 4194304 */
    const int d  = (fi & 63) * 4;
    float4 w4 = *(const float4*)&W[(size_t)gi[it]*DD + d];
    float4 z4 = *(const float4*)&ze[(size_t)fi*4];
    float4 o;
    o.x = z4.x + (w4.x - z4.x);
    o.y = z4.y + (w4.y - z4.y);
    o.z = z4.z + (w4.z - z4.z);
    o.w = z4.w + (w4.w - z4.w);
    *(float4*)&out[O_ZQ + (size_t)fi*4] = o;
    float dx;
    dx = w4.x - z4.x; distp += dx*dx;
    dx = w4.y - z4.y; distp += dx*dx;
    dx = w4.z - z4.z; distp += dx*dx;
    dx = w4.w - z4.w; distp += dx*dx;
  }
  #pragma unroll
  for (int m=1; m<64; m<<=1) distp += __shfl_xor(distp, m);
  if ((threadIdx.x & 63) == 0) dps[threadIdx.x >> 6] = distp;
  __syncthreads();
  if (threadIdx.x == 0) dist_part[blockIdx.x] = dps[0]+dps[1]+dps[2]+dps[3];
}

/* exclusive prefix sum over 1024 counts -> offs (with sentinel), pos */
__global__ __launch_bounds__(1024,1) void vq_prefix_kernel(
    const int* __restrict__ cnt, int* __restrict__ offs, int* __restrict__ pos)
{
  __shared__ int s[1024];
  const int tid = threadIdx.x;
  const int c = cnt[tid];
  s[tid] = c;
  __syncthreads();
  #pragma unroll
  for (int off=1; off<1024; off<<=1){
    int v = s[tid];
    int a = (tid >= off) ? s[tid-off] : 0;
    __syncthreads();
    s[tid] = v + a;
    __syncthreads();
  }
  const int ex = s[tid] - c;
  offs[tid] = ex;
  pos[tid]  = ex;
  if (tid == 1023) offs[1024] = NROWS;
}

/* bucket row ids by code */
__global__ __launch_bounds__(256,1) void vq_scatter_kernel(
    const int* __restrict__ rowcode, int* __restrict__ pos, int* __restrict__ bucket)
{
  const int r = blockIdx.x*256 + threadIdx.x;
  const int k = rowcode[r];
  const int slot = atomicAdd(&pos[k], 1);
  bucket[slot] = r;
}

/* chunksum (pure): 16-entry chunks, 1024 blocks x 4 waves. Segmented sum of
   ze rows over the code-sorted bucket; st flush at code boundaries only. */
__global__ __launch_bounds__(256,4) void vq_chunksum_kernel(
    const float* __restrict__ ze, const int* __restrict__ bucket,
    const int* __restrict__ offs, float* __restrict__ st)
{
  __shared__ int offsS[1025];
  const int tid = threadIdx.x;
  for (int i=tid; i<1025; i+=256) offsS[i] = offs[i];
  __syncthreads();

  const int wv = tid >> 6, lane = tid & 63;
  const int j0 = (blockIdx.x*4 + wv)*16;

  int r, k;
  {
    const int j = j0 + (lane & 15);
    r = bucket[j];
    int lo = 0, hi = 1024;
    #pragma unroll
    for (int it=0; it<10; ++it){
      int mid = (lo + hi) >> 1;
      if (offsS[mid] <= j) lo = mid; else hi = mid;
    }
    k = lo;
  }

  float4 acc = {0.f,0.f,0.f,0.f};
  int kprev = __shfl(k, 0);
  #pragma unroll
  for (int g=0; g<2; ++g){
    float4 v[8]; int rk[8];
    #pragma unroll
    for (int i=0;i<8;i++){
      const int ri = __shfl(r, g*8+i);
      rk[i] = __shfl(k, g*8+i);
      v[i] = *(const float4*)&ze[(size_t)ri*DD + lane*4];
    }
    #pragma unroll
    for (int i=0;i<8;i++){
      if (rk[i] != kprev){
        atomicAdd(&st[(size_t)kprev*DD + lane*4 + 0], acc.x);
        atomicAdd(&st[(size_t)kprev*DD + lane*4 + 1], acc.y);
        atomicAdd(&st[(size_t)kprev*DD + lane*4 + 2], acc.z);
        atomicAdd(&st[(size_t)kprev*DD + lane*4 + 3], acc.w);
        acc = (float4){0.f,0.f,0.f,0.f};
        kprev = rk[i];
      }
      acc.x += v[i].x; acc.y += v[i].y; acc.z += v[i].z; acc.w += v[i].w;
    }
  }
  atomicAdd(&st[(size_t)kprev*DD + lane*4 + 0], acc.x);
  atomicAdd(&st[(size_t)kprev*DD + lane*4 + 1], acc.y);
  atomicAdd(&st[(size_t)kprev*DD + lane*4 + 2], acc.z);
  atomicAdd(&st[(size_t)kprev*DD + lane*4 + 3], acc.w);
}

/* EMA tail: mt_new, embedW_new, Nt_new; block 0 also finalizes dist */
__global__ __launch_bounds__(256,1) void vq_tail_kernel(
    const float* __restrict__ mt, const float* __restrict__ Nt,
    const float* __restrict__ st, const int* __restrict__ cnt,
    const float* __restrict__ dist_part, float* __restrict__ out)
{
  const float G   = 0.99f;
  const float OMG = (float)(1.0 - 0.99);
  const int i = blockIdx.x*256 + threadIdx.x;   /* 0..KD-1 */
  const int k = i >> 8;
  const float ntn = __fadd_rn(__fmul_rn(G, Nt[k]), __fmul_rn(OMG, (float)cnt[k]));
  const float mtn = __fadd_rn(__fmul_rn(G, mt[i]), __fmul_rn(OMG, st[i]));
  out[O_MT  + i] = mtn;
  out[O_EMB + i] = mtn / ntn;
  if ((i & 255) == 0) out[O_NT + k] = ntn;

  if (blockIdx.x == 0){
    __shared__ float ds[4];
    const int tid = threadIdx.x;
    float s = 0.f;
    #pragma unroll
    for (int q=0; q<8; ++q) s += dist_part[tid + q*256];
    #pragma unroll
    for (int m=1; m<64; m<<=1) s += __shfl_xor(s, m);
    if ((tid & 63) == 0) ds[tid >> 6] = s;
    __syncthreads();
    if (tid == 0) out[O_DIST] = (ds[0]+ds[1]+ds[2]+ds[3]) * (1.0f/16777216.0f);
  }
}

extern "C" void kernel_launch(void* const* d_in, const int* in_sizes, int n_in,
                              void* d_out, int out_size, void* d_ws, size_t ws_size,
                              hipStream_t stream){
  const float* ze = (const float*)d_in[0];
  const float* W  = (const float*)d_in[1];
  const float* mt = (const float*)d_in[2];
  const float* Nt = (const float*)d_in[3];
  float* out  = (float*)d_out;
  float* ws   = (float*)d_ws;
  float*  wsq  = ws + WS_WSQ;
  bf16x8* wpk  = (bf16x8*)(ws + WS_WPK);
  int*    rowc = (int*)(ws + WS_ROWC);
  int*    buck = (int*)(ws + WS_BUCK);
  int*    offs = (int*)(ws + WS_OFFS);
  int*    pos  = (int*)(ws + WS_POS);
  int*    cnt  = (int*)(ws + WS_CNT);
  float*  st   = ws + WS_ST;
  unsigned short* cand = (unsigned short*)(ws + WS_CAND);
  unsigned short* selw = (unsigned short*)(ws + WS_SEL);
  float*  distp = ws + WS_DISTP;

  /* zero cnt + legacy dist slot + st in one shot (contiguous) */
  hipMemsetAsync((void*)(ws + WS_CNT), 0, (size_t)(KC + 4 + KD)*sizeof(float), stream);
  /* zero dist partials (2048 zq blocks) */
  hipMemsetAsync((void*)(ws + WS_DISTP), 0, 2048*sizeof(float), stream);
  vq_prep_kernel    <<<KC/4,        256, 0, stream>>>(W, wsq, wpk);
  vq_screen_kernel  <<<NROWS/BROWS, 512, 0, stream>>>(ze, wpk, wsq, cand, selw);
  vq_decide_kernel  <<<NROWS/256,   256, 0, stream>>>(ze, W, wsq, cand, selw, rowc, cnt, out);
  vq_zq_kernel      <<<2048,        256, 0, stream>>>(ze, W, rowc, out, distp);
  vq_prefix_kernel  <<<1,          1024, 0, stream>>>(cnt, offs, pos);
  vq_scatter_kernel <<<NROWS/256,   256, 0, stream>>>(rowc, pos, buck);
  vq_chunksum_kernel<<<NROWS/64,    256, 0, stream>>>(ze, buck, offs, st);
  vq_tail_kernel    <<<KD/256,      256, 0, stream>>>(mt, Nt, st, cnt, distp, out);
}

// Round 21
// 247.639 us; speedup vs baseline: 1.0820x; 1.0820x over previous
//
#include <hip/hip_runtime.h>

#define NROWS 65536
#define KC    1024
#define DD    256
#define ND    (NROWS*DD)      /* 16777216 */
#define KD    (KC*DD)         /* 262144 */
#define BROWS 64              /* rows per screen block */
#define CAP   32              /* LDS candidate list capacity per row */
#define CEXP  12              /* exported (filtered) candidates per row */
#define MARGIN 3.0f           /* >=2E for bf16-screen vs exact-replica (~14 sigma) */

/* output offsets (floats), concatenated in reference return order */
#define O_ZQ   0
#define O_DIST ND
#define O_IDX  (ND+1)
#define O_EMB  (ND+1+NROWS)
#define O_MT   (O_EMB+KD)
#define O_NT   (O_MT+KD)

/* ws float offsets */
#define WS_WSQ   0
#define WS_WPK   KC                    /* 131072 floats = 512KB bf16 W frags */
#define WS_ROWC  (KC+131072)           /* NROWS ints */
#define WS_BUCK  (WS_ROWC+NROWS)       /* NROWS ints */
#define WS_OFFS  (WS_BUCK+NROWS)       /* 1028 ints (1025 used) */
#define WS_POS   (WS_OFFS+1028)        /* KC ints */
#define WS_CNT   (WS_POS+KC)           /* KC ints */
#define WS_DIST  (WS_CNT+KC)           /* 1 float + 3 pad (legacy slot) */
#define WS_ST    (WS_DIST+4)           /* KD floats */
#define WS_CAND  (WS_ST+KD)            /* NROWS*CEXP u16 */
#define WS_SEL   (WS_CAND+NROWS*CEXP/2)/* NROWS u16 -> NROWS/2 floats */
#define WS_DISTP (WS_SEL+NROWS/2)      /* 1024 floats: per-block dist partials */

typedef __attribute__((ext_vector_type(8))) short bf16x8;
typedef __attribute__((ext_vector_type(4))) float f32x4;

/* ===== exact-replica arithmetic contract (validated rounds 5-20) =====
   ref dist d2[r][c] = fadd( fsub( zsq[r], fmul(2, dot) ), wsq[c] )
   dot  = sequential ascending-k, SEPARATE mul+add roundings, single acc
   zsq/wsq = strict sequential sum of squares (mul+add, ascending)
   argmin  = first occurrence of min.
   Screen = bf16 MFMA (row-constant zsq dropped, absorbed in MARGIN);
   every code within MARGIN of the row's global screen min is rescored
   with the exact chain.
   This round = r19 revert (best-known 252us: fused chunksum+zq) plus:
   - dist-partials memset dropped (chunksum writes all 1024 unconditionally)
   - prefix scan: 20-barrier Hillis-Steele -> 2-barrier wave shfl scan
     (identical offsets by construction). */

static __device__ __forceinline__ void minmerge(float& bv, int& bi, float ov, int oi){
  if (ov < bv || (ov == bv && oi < bi)) { bv = ov; bi = oi; }
}

static __device__ __forceinline__ unsigned short f2bf(float f){
  unsigned u = __float_as_uint(f);
  unsigned r = (u + 0x7FFFu + ((u>>16)&1u)) >> 16;   /* RNE */
  return (unsigned short)r;
}
static __device__ __forceinline__ bf16x8 cvt8(float4 a, float4 b){
  bf16x8 v;
  v[0]=(short)f2bf(a.x); v[1]=(short)f2bf(a.y); v[2]=(short)f2bf(a.z); v[3]=(short)f2bf(a.w);
  v[4]=(short)f2bf(b.x); v[5]=(short)f2bf(b.y); v[6]=(short)f2bf(b.z); v[7]=(short)f2bf(b.w);
  return v;
}

/* prologue: one wave per code. Lanes 0-31 pack bf16 B-fragments,
   lane 32 runs the exact wsq chain (scalar, round-11 verbatim). */
__global__ __launch_bounds__(256,1) void vq_prep_kernel(const float* __restrict__ W,
                                                        float* __restrict__ wsq,
                                                        bf16x8* __restrict__ wpk){
  const int wv = threadIdx.x>>6, lane = threadIdx.x&63;
  const int k = blockIdx.x*4 + wv;
  const float* wr = W + (size_t)k*DD;
  if (lane < 32){
    float4 x = *(const float4*)(wr + lane*8);
    float4 y = *(const float4*)(wr + lane*8 + 4);
    wpk[((k>>4)*8 + (lane>>2))*64 + (k&15) + 16*(lane&3)] = cvt8(x,y);
  } else if (lane == 32){
    float s = __fmul_rn(wr[0], wr[0]);
    for (int i=1;i<256;i++) s = __fadd_rn(s, __fmul_rn(wr[i], wr[i]));
    wsq[k] = s;
  }
}

/* screenA: r18 verbatim. 512 thr = 8 waves, 64 rows x 1024 codes per block,
   4 col passes of 64 -> acc[2][4], no spill at the arg2=4 cap (64). */
__global__ __launch_bounds__(512,4) void vq_screen_kernel(
    const float* __restrict__ ze, const bf16x8* __restrict__ wpk,
    const float* __restrict__ wsq,
    unsigned short* __restrict__ cand, unsigned short* __restrict__ selw)
{
  __shared__ bf16x8 apkS[2048];        /* 32 KB: A fragments, linear */
  __shared__ float  wsqS[KC];          /* 4 KB */
  __shared__ float  gminW[16][BROWS];  /* 4 KB: per-(pass,cg) row mins */
  __shared__ int    cntS[BROWS];
  __shared__ float  listV[BROWS][CAP]; /* 8 KB */
  __shared__ int    listI[BROWS][CAP]; /* 8 KB */

  const int tid = threadIdx.x;
  const int blk = blockIdx.x;
  const float* zb = ze + (size_t)blk*BROWS*DD;

  /* ---- phase 1: convert z tile to A fragments + init ---- */
  #pragma unroll
  for (int it=0; it<4; ++it){
    const int g  = it*512 + tid;
    const int r  = g >> 5;
    const int kb = g & 31;
    float4 a = *(const float4*)&zb[(size_t)r*DD + kb*8];
    float4 b = *(const float4*)&zb[(size_t)r*DD + kb*8 + 4];
    apkS[((r>>4)*8 + (kb>>2))*64 + (r&15) + 16*(kb&3)] = cvt8(a,b);
  }
  wsqS[tid]     = wsq[tid];
  wsqS[tid+512] = wsq[tid+512];
  if (tid < BROWS) cntS[tid] = 0;
  __syncthreads();

  /* ---- phase 2: MFMA screen + per-group min + candidate collection ---- */
  const int lane = tid & 63;
  const int wv   = tid >> 6;
  const int rg   = wv >> 2;
  const int cg   = wv & 3;

  for (int p=0; p<4; ++p){
    f32x4 acc[2][4];
    #pragma unroll
    for (int mt=0; mt<2; ++mt)
      #pragma unroll
      for (int nt=0; nt<4; ++nt)
        acc[mt][nt] = (f32x4){0.f,0.f,0.f,0.f};

    #pragma unroll
    for (int s=0; s<8; ++s){
      bf16x8 af[2], bf[4];
      #pragma unroll
      for (int mt=0; mt<2; ++mt)
        af[mt] = apkS[((rg*2+mt)*8 + s)*64 + lane];
      #pragma unroll
      for (int nt=0; nt<4; ++nt)
        bf[nt] = wpk[(size_t)(((cg*16 + p*4 + nt)*8 + s)*64 + lane)];
      #pragma unroll
      for (int mt=0; mt<2; ++mt)
        #pragma unroll
        for (int nt=0; nt<4; ++nt)
          acc[mt][nt] = __builtin_amdgcn_mfma_f32_16x16x32_bf16(af[mt], bf[nt], acc[mt][nt], 0,0,0);
    }

    /* screen value = wsq - 2*dot (row-constant zsq dropped) */
    #pragma unroll
    for (int mt=0; mt<2; ++mt){
      #pragma unroll
      for (int r=0; r<4; ++r){
        const int row = rg*32 + mt*16 + (lane>>4)*4 + r;
        float dv[4]; float mn = 3.4e38f;
        #pragma unroll
        for (int nt=0; nt<4; ++nt){
          const int col = (cg*16 + p*4 + nt)*16 + (lane&15);
          dv[nt] = __fsub_rn(wsqS[col], __fmul_rn(2.0f, acc[mt][nt][r]));
          mn = fminf(mn, dv[nt]);
        }
        #pragma unroll
        for (int m=1; m<16; m<<=1) mn = fminf(mn, __shfl_xor(mn, m));
        if ((lane & 15) == 0) gminW[p*4+cg][row] = mn;
        const float thr = mn + MARGIN;
        #pragma unroll
        for (int nt=0; nt<4; ++nt){
          if (dv[nt] <= thr){
            int slot = atomicAdd(&cntS[row], 1);
            if (slot < CAP){
              listV[row][slot] = dv[nt];
              listI[row][slot] = (cg*16 + p*4 + nt)*16 + (lane&15);
            }
          }
        }
      }
    }
  }
  __syncthreads();

  /* ---- phase 3': global-min filter + export ---- */
  if (tid < BROWS){
    const int rr = tid;
    float g = gminW[0][rr];
    #pragma unroll
    for (int q=1;q<16;q++) g = fminf(g, gminW[q][rr]);
    const float fthr = g + MARGIN;
    int c = cntS[rr]; if (c > CAP) c = CAP;
    const int grow = blk*BROWS + rr;
    int sel = 0;
    for (int i=0;i<c;i++){
      if (listV[rr][i] <= fthr && sel < CEXP){
        cand[(size_t)grow*CEXP + sel] = (unsigned short)listI[rr][i];
        sel++;
      }
    }
    selw[grow] = (unsigned short)sel;
  }
}

/* decideB: r19 verbatim. 1 thread/row, chains value-identical to r11. */
__global__ __launch_bounds__(256,1) void vq_decide_kernel(
    const float* __restrict__ ze, const float* __restrict__ W,
    const float* __restrict__ wsq,
    const unsigned short* __restrict__ cand, const unsigned short* __restrict__ selw,
    int* __restrict__ rowcode, int* __restrict__ cnt, float* __restrict__ out)
{
  const int row = blockIdx.x*256 + threadIdx.x;
  const float4* z4p = (const float4*)(ze + (size_t)row*DD);
  const int sel = selw[row];
  float bv = 3.4e38f; int bi = 0x7fffffff;

  if (sel > 0){
    const int idx0 = cand[(size_t)row*CEXP];
    const float4* w4p = (const float4*)(W + (size_t)idx0*DD);
    float4 z = z4p[0], w = w4p[0];
    float zs = __fmul_rn(z.x, z.x);
    float ss = __fadd_rn(0.f, __fmul_rn(z.x, w.x));
    zs = __fadd_rn(zs, __fmul_rn(z.y, z.y)); ss = __fadd_rn(ss, __fmul_rn(z.y, w.y));
    zs = __fadd_rn(zs, __fmul_rn(z.z, z.z)); ss = __fadd_rn(ss, __fmul_rn(z.z, w.z));
    zs = __fadd_rn(zs, __fmul_rn(z.w, z.w)); ss = __fadd_rn(ss, __fmul_rn(z.w, w.w));
    for (int k4=1; k4<64; ++k4){
      z = z4p[k4]; w = w4p[k4];
      zs = __fadd_rn(zs, __fmul_rn(z.x, z.x)); ss = __fadd_rn(ss, __fmul_rn(z.x, w.x));
      zs = __fadd_rn(zs, __fmul_rn(z.y, z.y)); ss = __fadd_rn(ss, __fmul_rn(z.y, w.y));
      zs = __fadd_rn(zs, __fmul_rn(z.z, z.z)); ss = __fadd_rn(ss, __fmul_rn(z.z, w.z));
      zs = __fadd_rn(zs, __fmul_rn(z.w, z.w)); ss = __fadd_rn(ss, __fmul_rn(z.w, w.w));
    }
    {
      const float v = __fadd_rn(__fsub_rn(zs, __fmul_rn(2.0f, ss)), wsq[idx0]);
      minmerge(bv, bi, v, idx0);
    }
    for (int i=1; i<sel; ++i){
      const int idx = cand[(size_t)row*CEXP + i];
      const float4* wp = (const float4*)(W + (size_t)idx*DD);
      float s2 = 0.f;
      for (int k4=0; k4<64; ++k4){
        float4 zz = z4p[k4], ww = wp[k4];
        s2 = __fadd_rn(s2, __fmul_rn(zz.x, ww.x));
        s2 = __fadd_rn(s2, __fmul_rn(zz.y, ww.y));
        s2 = __fadd_rn(s2, __fmul_rn(zz.z, ww.z));
        s2 = __fadd_rn(s2, __fmul_rn(zz.w, ww.w));
      }
      const float v = __fadd_rn(__fsub_rn(zs, __fmul_rn(2.0f, s2)), wsq[idx]);
      minmerge(bv, bi, v, idx);
    }
  }
  rowcode[row] = bi;
  out[O_IDX + row] = (float)bi;
  atomicAdd(&cnt[bi], 1);
}

/* exclusive prefix sum over 1024 counts -> offs (with sentinel), pos.
   2-barrier wave shfl scan (identical results to the Hillis-Steele version). */
__global__ __launch_bounds__(1024,1) void vq_prefix_kernel(
    const int* __restrict__ cnt, int* __restrict__ offs, int* __restrict__ pos)
{
  __shared__ int wsum[16];
  const int tid  = threadIdx.x;
  const int wv   = tid >> 6;
  const int lane = tid & 63;
  const int c = cnt[tid];
  /* inclusive scan within wave */
  int x = c;
  #pragma unroll
  for (int off=1; off<64; off<<=1){
    int y = __shfl_up(x, off);
    if (lane >= off) x += y;
  }
  if (lane == 63) wsum[wv] = x;
  __syncthreads();
  if (tid < 16){
    int y = wsum[tid];
    #pragma unroll
    for (int off=1; off<16; off<<=1){
      int z = __shfl_up(y, off);
      if (tid >= off) y += z;
    }
    wsum[tid] = y;   /* inclusive wave totals */
  }
  __syncthreads();
  const int base = (wv > 0) ? wsum[wv-1] : 0;
  const int ex = base + x - c;   /* exclusive prefix */
  offs[tid] = ex;
  pos[tid]  = ex;
  if (tid == 1023) offs[1024] = NROWS;
}

/* bucket row ids by code */
__global__ __launch_bounds__(256,1) void vq_scatter_kernel(
    const int* __restrict__ rowcode, int* __restrict__ pos, int* __restrict__ bucket)
{
  const int r = blockIdx.x*256 + threadIdx.x;
  const int k = rowcode[r];
  const int slot = atomicAdd(&pos[k], 1);
  bucket[slot] = r;
}

/* chunksum + fused zq epilogue (r19 verbatim): 16-entry chunks, 1024 blocks
   x 4 waves. st flush at code boundaries; zq_st write + dist partials. */
__global__ __launch_bounds__(256,4) void vq_chunksum_kernel(
    const float* __restrict__ ze, const float* __restrict__ W,
    const int* __restrict__ bucket, const int* __restrict__ offs,
    float* __restrict__ st, float* __restrict__ out,
    float* __restrict__ dist_part)
{
  __shared__ int offsS[1025];
  __shared__ float dps[4];
  const int tid = threadIdx.x;
  for (int i=tid; i<1025; i+=256) offsS[i] = offs[i];
  __syncthreads();

  const int wv = tid >> 6, lane = tid & 63;
  const int j0 = (blockIdx.x*4 + wv)*16;

  int r, k;
  {
    const int j = j0 + (lane & 15);
    r = bucket[j];
    int lo = 0, hi = 1024;
    #pragma unroll
    for (int it=0; it<10; ++it){
      int mid = (lo + hi) >> 1;
      if (offsS[mid] <= j) lo = mid; else hi = mid;
    }
    k = lo;
  }

  float4 acc = {0.f,0.f,0.f,0.f};
  float distp = 0.f;
  int kprev = __shfl(k, 0);
  #pragma unroll
  for (int g=0; g<2; ++g){
    float4 v[8]; int rk[8]; int rr[8];
    #pragma unroll
    for (int i=0;i<8;i++){
      rr[i] = __shfl(r, g*8+i);
      rk[i] = __shfl(k, g*8+i);
      v[i] = *(const float4*)&ze[(size_t)rr[i]*DD + lane*4];
    }
    #pragma unroll
    for (int i=0;i<8;i++){
      if (rk[i] != kprev){
        atomicAdd(&st[(size_t)kprev*DD + lane*4 + 0], acc.x);
        atomicAdd(&st[(size_t)kprev*DD + lane*4 + 1], acc.y);
        atomicAdd(&st[(size_t)kprev*DD + lane*4 + 2], acc.z);
        atomicAdd(&st[(size_t)kprev*DD + lane*4 + 3], acc.w);
        acc = (float4){0.f,0.f,0.f,0.f};
        kprev = rk[i];
      }
      acc.x += v[i].x; acc.y += v[i].y; acc.z += v[i].z; acc.w += v[i].w;
      /* fused zq epilogue for this row (reference formula) */
      float4 w4 = *(const float4*)&W[(size_t)rk[i]*DD + lane*4];
      float4 o;
      o.x = v[i].x + (w4.x - v[i].x);
      o.y = v[i].y + (w4.y - v[i].y);
      o.z = v[i].z + (w4.z - v[i].z);
      o.w = v[i].w + (w4.w - v[i].w);
      *(float4*)&out[O_ZQ + (size_t)rr[i]*DD + lane*4] = o;
      float dx;
      dx = w4.x - v[i].x; distp += dx*dx;
      dx = w4.y - v[i].y; distp += dx*dx;
      dx = w4.z - v[i].z; distp += dx*dx;
      dx = w4.w - v[i].w; distp += dx*dx;
    }
  }
  atomicAdd(&st[(size_t)kprev*DD + lane*4 + 0], acc.x);
  atomicAdd(&st[(size_t)kprev*DD + lane*4 + 1], acc.y);
  atomicAdd(&st[(size_t)kprev*DD + lane*4 + 2], acc.z);
  atomicAdd(&st[(size_t)kprev*DD + lane*4 + 3], acc.w);

  /* dist: wave reduce -> block partial (written unconditionally for ALL
     1024 blocks, so no memset of dist_part is needed) */
  #pragma unroll
  for (int m=1; m<64; m<<=1) distp += __shfl_xor(distp, m);
  if (lane == 0) dps[wv] = distp;
  __syncthreads();
  if (tid == 0) dist_part[blockIdx.x] = dps[0]+dps[1]+dps[2]+dps[3];
}

/* EMA tail: mt_new, embedW_new, Nt_new; block 0 also finalizes dist */
__global__ __launch_bounds__(256,1) void vq_tail_kernel(
    const float* __restrict__ mt, const float* __restrict__ Nt,
    const float* __restrict__ st, const int* __restrict__ cnt,
    const float* __restrict__ dist_part, float* __restrict__ out)
{
  const float G   = 0.99f;
  const float OMG = (float)(1.0 - 0.99);
  const int i = blockIdx.x*256 + threadIdx.x;   /* 0..KD-1 */
  const int k = i >> 8;
  const float ntn = __fadd_rn(__fmul_rn(G, Nt[k]), __fmul_rn(OMG, (float)cnt[k]));
  const float mtn = __fadd_rn(__fmul_rn(G, mt[i]), __fmul_rn(OMG, st[i]));
  out[O_MT  + i] = mtn;
  out[O_EMB + i] = mtn / ntn;
  if ((i & 255) == 0) out[O_NT + k] = ntn;

  if (blockIdx.x == 0){
    __shared__ float ds[4];
    const int tid = threadIdx.x;
    float s = 0.f;
    #pragma unroll
    for (int q=0; q<4; ++q) s += dist_part[tid + q*256];
    #pragma unroll
    for (int m=1; m<64; m<<=1) s += __shfl_xor(s, m);
    if ((tid & 63) == 0) ds[tid >> 6] = s;
    __syncthreads();
    if (tid == 0) out[O_DIST] = (ds[0]+ds[1]+ds[2]+ds[3]) * (1.0f/16777216.0f);
  }
}

extern "C" void kernel_launch(void* const* d_in, const int* in_sizes, int n_in,
                              void* d_out, int out_size, void* d_ws, size_t ws_size,
                              hipStream_t stream){
  const float* ze = (const float*)d_in[0];
  const float* W  = (const float*)d_in[1];
  const float* mt = (const float*)d_in[2];
  const float* Nt = (const float*)d_in[3];
  float* out  = (float*)d_out;
  float* ws   = (float*)d_ws;
  float*  wsq  = ws + WS_WSQ;
  bf16x8* wpk  = (bf16x8*)(ws + WS_WPK);
  int*    rowc = (int*)(ws + WS_ROWC);
  int*    buck = (int*)(ws + WS_BUCK);
  int*    offs = (int*)(ws + WS_OFFS);
  int*    pos  = (int*)(ws + WS_POS);
  int*    cnt  = (int*)(ws + WS_CNT);
  float*  st   = ws + WS_ST;
  unsigned short* cand = (unsigned short*)(ws + WS_CAND);
  unsigned short* selw = (unsigned short*)(ws + WS_SEL);
  float*  distp = ws + WS_DISTP;

  /* zero cnt + legacy dist slot + st in one shot (contiguous) */
  hipMemsetAsync((void*)(ws + WS_CNT), 0, (size_t)(KC + 4 + KD)*sizeof(float), stream);
  vq_prep_kernel    <<<KC/4,        256, 0, stream>>>(W, wsq, wpk);
  vq_screen_kernel  <<<NROWS/BROWS, 512, 0, stream>>>(ze, wpk, wsq, cand, selw);
  vq_decide_kernel  <<<NROWS/256,   256, 0, stream>>>(ze, W, wsq, cand, selw, rowc, cnt, out);
  vq_prefix_kernel  <<<1,          1024, 0, stream>>>(cnt, offs, pos);
  vq_scatter_kernel <<<NROWS/256,   256, 0, stream>>>(rowc, pos, buck);
  vq_chunksum_kernel<<<NROWS/64,    256, 0, stream>>>(ze, W, buck, offs, st, out, distp);
  vq_tail_kernel    <<<KD/256,      256, 0, stream>>>(mt, Nt, st, cnt, distp, out);
}